// Round 15
// baseline (161.027 us; speedup 1.0000x reference)
//
#include <hip/hip_runtime.h>
#include <hip/hip_bf16.h>

typedef __bf16 bf16_t;
typedef __attribute__((ext_vector_type(8))) __bf16 bf16x8;
typedef __attribute__((ext_vector_type(4))) float f32x4;

#define MFMA16(a, b, c) __builtin_amdgcn_mfma_f32_16x16x32_bf16((a), (b), (c), 0, 0, 0)

// Problem sizes
#define NB 8
#define SS 2048
#define DM 1024
#define DK 64
#define NROW (NB * SS)  // 16384
#define NSPLIT 4
#define SPLEN (SS / NSPLIT)  // 512

typedef __attribute__((address_space(1))) const unsigned int ga_u32;
typedef __attribute__((address_space(3))) unsigned int ls_u32;
#define GLOAD16(g, l) \
  __builtin_amdgcn_global_load_lds((ga_u32*)(g), (ls_u32*)(l), 16, 0, 0)

union U16x8 { unsigned short u[8]; uint4 q; };
union U16x4 { unsigned short u[4]; ushort4 v; };

__device__ inline void split_hl(float x, unsigned short& h, unsigned short& l) {
  bf16_t hb = (bf16_t)x;
  bf16_t lb = (bf16_t)(x - (float)hb);
  h = *(unsigned short*)&hb;
  l = *(unsigned short*)&lb;
}

// ---------------- kernel 0: pack mask (int32 0/1) into bits ----------------
__global__ __launch_bounds__(256) void maskpack_kernel(
    const int* __restrict__ mask, unsigned int* __restrict__ mbits) {
  int idx = blockIdx.x * 256 + threadIdx.x;  // word index: q*64 + w
  int q = idx >> 6, w = idx & 63;
  const int4* src = (const int4*)(mask + (q << 11) + (w << 5));
  unsigned int bits = 0u;
#pragma unroll
  for (int i = 0; i < 8; ++i) {
    int4 t = src[i];
    bits |= (t.x != 0 ? 1u : 0u) << (i * 4 + 0);
    bits |= (t.y != 0 ? 1u : 0u) << (i * 4 + 1);
    bits |= (t.z != 0 ? 1u : 0u) << (i * 4 + 2);
    bits |= (t.w != 0 ? 1u : 0u) << (i * 4 + 3);
  }
  mbits[idx] = bits;
}

// ------------- kernel 0b: W -> LDS-ready swizzled tile images ---------------
// wimg layout: [3 modes][16 chunks][16KB]; per chunk: hi 8KB + lo 8KB,
// byte(n, kk) = n*128 + ((2*kk) ^ ((n&7)<<4)),  n=out-col 0..63, kk=k&63.
__global__ __launch_bounds__(256) void wprep_kernel(
    const float* __restrict__ Wq, const float* __restrict__ Wk,
    const float* __restrict__ Wv, char* __restrict__ wimg) {
  int which = blockIdx.x >> 6;
  const float* W = which == 0 ? Wq : (which == 1 ? Wk : Wv);
  char* img = wimg + (size_t)which * 16 * 16384;
  int e = (blockIdx.x & 63) * 256 + threadIdx.x;  // 16384 threads per mode
  int k = e >> 4, n0 = (e & 15) << 2;
  float4 f = *(const float4*)(W + k * 64 + n0);
  float fv[4] = {f.x, f.y, f.z, f.w};
  char* base = img + (k >> 6) * 16384;
  int kk = k & 63;
#pragma unroll
  for (int u = 0; u < 4; ++u) {
    int n = n0 + u;
    unsigned short h, l;
    split_hl(fv[u], h, l);
    int byte = n * 128 + ((2 * kk) ^ ((n & 7) << 4));
    *(unsigned short*)(base + byte) = h;
    *(unsigned short*)(base + 8192 + byte) = l;
  }
}

// ---------------- kernel 1: fused Q/K/V projection (pipelined GEMM) ---------
// Block = 64 rows x 64 cols, 4 waves. K-chunks of 64, software-pipelined:
//  - W chunk images double-buffered via global_load_lds, counted vmcnt(4)
//  - X chunk prefetched to registers one chunk ahead, NON-TEMPORAL loads
//    (bypass L2 so the 192MB X stream doesn't evict the L2-hot W images)
//  - raw s_barrier + manual lgkmcnt so prefetches stay in flight
__global__ __launch_bounds__(256) void proj3_kernel(
    const float* __restrict__ qx, const float* __restrict__ kx,
    const float* __restrict__ vx, const char* __restrict__ wimg,
    const float* __restrict__ bq, const float* __restrict__ bk,
    const float* __restrict__ bv, bf16_t* __restrict__ qhi,
    bf16_t* __restrict__ qlo, char* __restrict__ kimg,
    char* __restrict__ vimg) {
  __shared__ __align__(16) char smem[49152];
  char* xbuf = smem;  // X tile image: hi 8KB + lo 8KB (single-buffered)
  const int mode = blockIdx.y;
  const float* X = mode == 0 ? qx : (mode == 1 ? kx : vx);
  const float* bias = mode == 0 ? bq : (mode == 1 ? bk : bv);
  const int tid = threadIdx.x;
  const int lane = tid & 63;
  const int wv = tid >> 6;
  const int lr = lane & 15;
  const int g = lane >> 4;
  const int rbase = blockIdx.x * 64;
  const int xr = tid >> 2;             // staging row 0..63
  const int kg = (tid & 3) << 4;       // staging k-offset (floats)
  const int row_local = wv * 16 + lr;  // compute A row
  const int swa = (row_local & 7) << 4;
  const int swx = (xr & 7) << 4;

  f32x4 acc[4] = {};
  const char* wsrc0 = wimg + (size_t)mode * 16 * 16384;

  f32x4 xa, xb, xc, xd;  // in-flight X chunk (16 floats)
  auto issueX = [&](int ch) {
    const f32x4* xp =
        (const f32x4*)(X + (size_t)(rbase + xr) * DM + ch * 64 + kg);
    xa = __builtin_nontemporal_load(xp);
    xb = __builtin_nontemporal_load(xp + 1);
    xc = __builtin_nontemporal_load(xp + 2);
    xd = __builtin_nontemporal_load(xp + 3);
  };
  auto writeX = [&]() {
    float xv[16] = {xa[0], xa[1], xa[2], xa[3], xb[0], xb[1], xb[2], xb[3],
                    xc[0], xc[1], xc[2], xc[3], xd[0], xd[1], xd[2], xd[3]};
    U16x8 hq[2], lq[2];
#pragma unroll
    for (int i = 0; i < 16; ++i)
      split_hl(xv[i], hq[i >> 3].u[i & 7], lq[i >> 3].u[i & 7]);
    char* xh = xbuf + xr * 128;
    int b0 = 2 * kg;
    *(uint4*)(xh + (b0 ^ swx)) = hq[0].q;
    *(uint4*)(xh + ((b0 + 16) ^ swx)) = hq[1].q;
    *(uint4*)(xh + 8192 + (b0 ^ swx)) = lq[0].q;
    *(uint4*)(xh + 8192 + ((b0 + 16) ^ swx)) = lq[1].q;
  };
  auto stageW = [&](int ch, char* dst) {
    const char* wsrc = wsrc0 + ch * 16384;
#pragma unroll
    for (int u = 0; u < 4; ++u)
      GLOAD16(wsrc + u * 4096 + tid * 16, dst + u * 4096 + tid * 16);
  };
  auto compute = [&](const char* wb) {
#pragma unroll
    for (int ks = 0; ks < 2; ++ks) {
      int co = ks * 64 + g * 16;
      bf16x8 ah = *(const bf16x8*)(xbuf + row_local * 128 + (co ^ swa));
      bf16x8 al = *(const bf16x8*)(xbuf + 8192 + row_local * 128 + (co ^ swa));
#pragma unroll
      for (int c = 0; c < 4; ++c) {
        int n = c * 16 + lr;
        int swb = (n & 7) << 4;
        bf16x8 bh = *(const bf16x8*)(wb + n * 128 + (co ^ swb));
        bf16x8 bl = *(const bf16x8*)(wb + 8192 + n * 128 + (co ^ swb));
        acc[c] = MFMA16(ah, bl, acc[c]);
        acc[c] = MFMA16(al, bh, acc[c]);
        acc[c] = MFMA16(ah, bh, acc[c]);
      }
    }
  };

  // ---- prologue: fill X(0)+W(0), leave X(1)+nothing in flight ----
  issueX(0);
  stageW(0, smem + 16384);
  writeX();     // compiler inserts the wait for X(0)
  issueX(1);    // X(1) in flight (4 newer than W(0)'s 4)
  asm volatile("s_waitcnt vmcnt(4)" ::: "memory");   // W(0) landed
  asm volatile("s_waitcnt lgkmcnt(0)" ::: "memory"); // xbuf writes done
  __builtin_amdgcn_s_barrier();
  __builtin_amdgcn_sched_barrier(0);

  for (int ch = 0; ch < 16; ++ch) {
    char* wc = (ch & 1) ? smem + 32768 : smem + 16384;
    char* wn = (ch & 1) ? smem + 16384 : smem + 32768;
    if (ch < 15) stageW(ch + 1, wn);  // issue next W before compute
    compute(wc);
    if (ch < 15) {
      __builtin_amdgcn_sched_barrier(0);
      __builtin_amdgcn_s_barrier();  // all waves done reading xbuf
      __builtin_amdgcn_sched_barrier(0);
      writeX();  // X(ch+1) regs -> xbuf (compiler waits the X loads)
      if (ch < 14) {
        issueX(ch + 2);
        // outstanding: W(ch+1)=4 older, X(ch+2)=4 newer -> wait W done
        asm volatile("s_waitcnt vmcnt(4)" ::: "memory");
      } else {
        asm volatile("s_waitcnt vmcnt(0)" ::: "memory");
      }
      asm volatile("s_waitcnt lgkmcnt(0)" ::: "memory");
      __builtin_amdgcn_s_barrier();
      __builtin_amdgcn_sched_barrier(0);
    }
  }
  // ---- epilogue: stage acc to LDS [64][69] fp32, then mode-specific emit ---
  __syncthreads();
  float* sacc = (float*)smem;
#pragma unroll
  for (int c = 0; c < 4; ++c)
#pragma unroll
    for (int j = 0; j < 4; ++j)
      sacc[(wv * 16 + g * 4 + j) * 69 + c * 16 + lr] = acc[c][j];
  __syncthreads();

  const int b = rbase >> 11;
  const int t = (rbase & (SS - 1)) >> 6;
  if (mode == 0) {
    int r = tid & 63, cg = tid >> 6;
    int row = rbase + r;
    U16x8 h0, h1, l0, l1;
#pragma unroll
    for (int i = 0; i < 16; ++i) {
      float v = sacc[r * 69 + cg * 16 + i] + bias[cg * 16 + i];
      if (i < 8) split_hl(v, h0.u[i & 7], l0.u[i & 7]);
      else       split_hl(v, h1.u[i & 7], l1.u[i & 7]);
    }
    *(uint4*)((char*)qhi + (size_t)row * 128 + cg * 32) = h0.q;
    *(uint4*)((char*)qhi + (size_t)row * 128 + cg * 32 + 16) = h1.q;
    *(uint4*)((char*)qlo + (size_t)row * 128 + cg * 32) = l0.q;
    *(uint4*)((char*)qlo + (size_t)row * 128 + cg * 32 + 16) = l1.q;
  } else if (mode == 1) {
    int r = tid & 63, cg = tid >> 6;
    char* base = kimg + (((size_t)(b * 32 + t)) << 14);
    int sw = (r & 7) << 4;
#pragma unroll
    for (int m = 0; m < 4; ++m) {
      U16x4 hv, lv;
#pragma unroll
      for (int u = 0; u < 4; ++u) {
        int col = cg * 16 + m * 4 + u;
        float v = sacc[r * 69 + col] + bias[col];
        split_hl(v, hv.u[u], lv.u[u]);
      }
      int off = (cg * 32 + m * 8) ^ sw;
      *(ushort4*)(base + r * 128 + off) = hv.v;
      *(ushort4*)(base + 8192 + r * 128 + off) = lv.v;
    }
  } else {
    int d = tid & 63, rg = tid >> 6;
    char* base = vimg + (((size_t)(b * 32 + t)) << 14);
    int sw = (d & 7) << 4;
    float bv = bias[d];
#pragma unroll
    for (int m = 0; m < 4; ++m) {
      U16x4 hv, lv;
#pragma unroll
      for (int u = 0; u < 4; ++u) {
        int r = rg * 16 + m * 4 + u;
        float v = sacc[r * 69 + d] + bv;
        split_hl(v, hv.u[u], lv.u[u]);
      }
      int off = (rg * 32 + m * 8) ^ sw;
      *(ushort4*)(base + d * 128 + off) = hv.v;
      *(ushort4*)(base + 8192 + d * 128 + off) = lv.v;
    }
  }
}

// ---------------- kernel 2: flash attention (split-KV, LDS-shared) --------
__global__ __launch_bounds__(256) void attn_kernel(
    const bf16_t* __restrict__ qhi, const bf16_t* __restrict__ qlo,
    const char* __restrict__ kimg, const char* __restrict__ vimg,
    const unsigned int* __restrict__ mbits, float* __restrict__ part_acc,
    float* __restrict__ part_m, float* __restrict__ part_l) {
  __shared__ __align__(16) char kbuf[16384];
  __shared__ __align__(16) char vbuf[16384];
  __shared__ __align__(16) char plds_all[4][2048];
  const int tid = threadIdx.x;
  const int lane = tid & 63;
  const int wv = tid >> 6;
  const int lr = lane & 15;
  const int g = lane >> 4;
  char* plds = &plds_all[wv][0];
  const int qrow0 = (blockIdx.x * 4 + wv) * 16;
  const int split = blockIdx.y;
  const int kv0 = split * SPLEN;
  const int b = qrow0 >> 11;
  const int sq0 = (qrow0 & (SS - 1)) + g * 4;  // mask row base (per j)

  const bf16_t* qh = qhi + (qrow0 + lr) * DK + g * 8;
  const bf16_t* ql = qlo + (qrow0 + lr) * DK + g * 8;
  bf16x8 qh0 = *(const bf16x8*)qh;
  bf16x8 qh1 = *(const bf16x8*)(qh + 32);
  bf16x8 ql0 = *(const bf16x8*)ql;
  bf16x8 ql1 = *(const bf16x8*)(ql + 32);

  float m[4], lsum[4];
  f32x4 acc[4] = {};
#pragma unroll
  for (int j = 0; j < 4; ++j) { m[j] = -3.0e38f; lsum[j] = 0.f; }

  for (int it = 0; it < SPLEN / 64; ++it) {
    const int tglob = (kv0 >> 6) + it;
    const char* ksrc = kimg + (((size_t)(b * 32 + tglob)) << 14);
    const char* vsrc = vimg + (((size_t)(b * 32 + tglob)) << 14);
#pragma unroll
    for (int u = 0; u < 4; ++u) {
      GLOAD16(ksrc + tid * 16 + u * 4096, kbuf + tid * 16 + u * 4096);
      GLOAD16(vsrc + tid * 16 + u * 4096, vbuf + tid * 16 + u * 4096);
    }
    asm volatile("s_waitcnt vmcnt(0)\n" ::: "memory");
    __syncthreads();
    // QK^T over 64-key tile
    f32x4 sac[4];
#pragma unroll
    for (int t = 0; t < 4; ++t) {
      int rk = t * 16 + lr;
      int sw = (rk & 7) << 4;
      bf16x8 kh0 = *(const bf16x8*)(kbuf + rk * 128 + ((g * 16) ^ sw));
      bf16x8 kh1 = *(const bf16x8*)(kbuf + rk * 128 + ((64 + g * 16) ^ sw));
      bf16x8 kl0 = *(const bf16x8*)(kbuf + 8192 + rk * 128 + ((g * 16) ^ sw));
      bf16x8 kl1 =
          *(const bf16x8*)(kbuf + 8192 + rk * 128 + ((64 + g * 16) ^ sw));
      f32x4 s = {};
      s = MFMA16(qh0, kl0, s);
      s = MFMA16(qh1, kl1, s);
      s = MFMA16(ql0, kh0, s);
      s = MFMA16(ql1, kh1, s);
      s = MFMA16(qh0, kh0, s);
      s = MFMA16(qh1, kh1, s);
      sac[t] = s;
    }
    // mask: 2 words per row cover this 64-key tile
    const int wbase = (kv0 >> 5) + it * 2;
    uint2 m2[4];
#pragma unroll
    for (int j = 0; j < 4; ++j)
      m2[j] = *(const uint2*)(mbits + (sq0 + j) * 64 + wbase);
#pragma unroll
    for (int t = 0; t < 4; ++t)
#pragma unroll
      for (int j = 0; j < 4; ++j) {
        unsigned w = (t & 2) ? m2[j].y : m2[j].x;
        if (!((w >> ((t & 1) * 16 + lr)) & 1u)) sac[t][j] = -1e9f;
      }
    // online softmax
#pragma unroll
    for (int j = 0; j < 4; ++j) {
      float v = sac[0][j];
#pragma unroll
      for (int t = 1; t < 4; ++t) v = fmaxf(v, sac[t][j]);
      v = fmaxf(v, __shfl_xor(v, 1, 64));
      v = fmaxf(v, __shfl_xor(v, 2, 64));
      v = fmaxf(v, __shfl_xor(v, 4, 64));
      v = fmaxf(v, __shfl_xor(v, 8, 64));
      float mn = fmaxf(m[j], v);
      float sc = __expf(m[j] - mn);
      m[j] = mn;
      lsum[j] *= sc;
#pragma unroll
      for (int c = 0; c < 4; ++c) acc[c][j] *= sc;
    }
    // P = exp(s - m) -> wave-private swizzled LDS
    float ps[4] = {0.f, 0.f, 0.f, 0.f};
#pragma unroll
    for (int t = 0; t < 4; ++t)
#pragma unroll
      for (int j = 0; j < 4; ++j) {
        float p = __expf(sac[t][j] - m[j]);
        bf16_t pb = (bf16_t)p;
        ps[j] += (float)pb;  // lsum over ROUNDED p -> exact convex combo
        int row = g * 4 + j;
        int byte = row * 128 + (((t * 16 + lr) * 2) ^ ((row & 7) << 4));
        *(bf16_t*)(plds + byte) = pb;
      }
#pragma unroll
    for (int j = 0; j < 4; ++j) {
      float s_ = ps[j];
      s_ += __shfl_xor(s_, 1, 64);
      s_ += __shfl_xor(s_, 2, 64);
      s_ += __shfl_xor(s_, 4, 64);
      s_ += __shfl_xor(s_, 8, 64);
      lsum[j] += s_;
    }
    asm volatile("s_waitcnt lgkmcnt(0)\n" ::: "memory");
    // PV: A = P (transposed LDS read), B = V hi + lo from vbuf
#pragma unroll
    for (int kt = 0; kt < 2; ++kt) {
      int pbyte = lr * 128 + ((kt * 64 + g * 16) ^ ((lr & 7) << 4));
      bf16x8 pa = *(const bf16x8*)(plds + pbyte);
#pragma unroll
      for (int c = 0; c < 4; ++c) {
        int n = c * 16 + lr;
        int swv = (n & 7) << 4;
        bf16x8 vfh = *(const bf16x8*)(vbuf + n * 128 + ((kt * 64 + g * 16) ^ swv));
        bf16x8 vfl =
            *(const bf16x8*)(vbuf + 8192 + n * 128 + ((kt * 64 + g * 16) ^ swv));
        acc[c] = MFMA16(pa, vfh, acc[c]);
        acc[c] = MFMA16(pa, vfl, acc[c]);
      }
    }
    __syncthreads();  // all waves done reading kbuf/vbuf before next stage
  }
  // epilogue: write unnormalized partials
#pragma unroll
  for (int c = 0; c < 4; ++c)
#pragma unroll
    for (int j = 0; j < 4; ++j)
      part_acc[((size_t)split * NROW + qrow0 + g * 4 + j) * DK + c * 16 + lr] =
          acc[c][j];
  if (lr == 0) {
#pragma unroll
    for (int j = 0; j < 4; ++j) {
      part_m[split * NROW + qrow0 + g * 4 + j] = m[j];
      part_l[split * NROW + qrow0 + g * 4 + j] = lsum[j];
    }
  }
}

// ---------------- kernel 2b: combine split-KV partials ----------------
__global__ __launch_bounds__(256) void combine_kernel(
    const float* __restrict__ pacc, const float* __restrict__ pm,
    const float* __restrict__ pl, float* __restrict__ attn_f) {
  int idx = blockIdx.x * 256 + threadIdx.x;
  int row = idx >> 6;
  float m0 = pm[row], m1 = pm[NROW + row];
  float m2 = pm[2 * NROW + row], m3 = pm[3 * NROW + row];
  float M = fmaxf(fmaxf(m0, m1), fmaxf(m2, m3));
  float w0 = __expf(m0 - M), w1 = __expf(m1 - M);
  float w2 = __expf(m2 - M), w3 = __expf(m3 - M);
  float l = w0 * pl[row] + w1 * pl[NROW + row] + w2 * pl[2 * NROW + row] +
            w3 * pl[3 * NROW + row];
  float a = w0 * pacc[idx] + w1 * pacc[(size_t)NROW * DK + idx] +
            w2 * pacc[2 * (size_t)NROW * DK + idx] +
            w3 * pacc[3 * (size_t)NROW * DK + idx];
  attn_f[idx] = a / l;
}

// ---------------- kernel 3: output projection  out = A @ Wo + bo ----------
__global__ __launch_bounds__(256) void oproj_kernel(
    const float* __restrict__ attn, const float* __restrict__ Wo,
    const float* __restrict__ bo, float* __restrict__ out) {
  __shared__ __align__(16) bf16_t wt[256 * 64];  // Wo^T chunk [n][k], swizzled
  const int tid = threadIdx.x;
  const int lane = tid & 63;
  const int wv = tid >> 6;
  const int lr = lane & 15;
  const int g = lane >> 4;
  const int rbase = blockIdx.x * 64 + wv * 16;
  const int c0 = blockIdx.y * 256;
  {  // stage Wo[0..64][c0..c0+256] -> wt[n][k]
    const int k = tid >> 2;
    const int n0 = (tid & 3) << 6;
    const float4* src = (const float4*)(Wo + k * DM + c0 + n0);
#pragma unroll
    for (int i = 0; i < 16; ++i) {
      float4 f = src[i];
      float fv[4] = {f.x, f.y, f.z, f.w};
#pragma unroll
      for (int u = 0; u < 4; ++u) {
        int n = n0 + i * 4 + u;
        int byte = (n << 7) + (k << 1);
        byte ^= (n & 7) << 4;
        *(bf16_t*)((char*)wt + byte) = (bf16_t)fv[u];
      }
    }
  }
  __syncthreads();
  const float* ab = attn + (rbase + lr) * DK + g * 8;
  float4 x0 = *(const float4*)ab;
  float4 x1 = *(const float4*)(ab + 4);
  float4 y0 = *(const float4*)(ab + 32);
  float4 y1 = *(const float4*)(ab + 36);
  float xv[8] = {x0.x, x0.y, x0.z, x0.w, x1.x, x1.y, x1.z, x1.w};
  float yv[8] = {y0.x, y0.y, y0.z, y0.w, y1.x, y1.y, y1.z, y1.w};
  bf16x8 ah0, al0, ah1, al1;
#pragma unroll
  for (int i = 0; i < 8; ++i) {
    ah0[i] = (bf16_t)xv[i];
    al0[i] = (bf16_t)(xv[i] - (float)ah0[i]);
    ah1[i] = (bf16_t)yv[i];
    al1[i] = (bf16_t)(yv[i] - (float)ah1[i]);
  }
  f32x4 acc[16] = {};
#pragma unroll
  for (int c = 0; c < 16; ++c) {
    int n = c * 16 + lr;
    int byte0 = (n << 7) + ((g * 8) << 1);
    byte0 ^= (n & 7) << 4;
    int byte1 = (n << 7) + ((32 + g * 8) << 1);
    byte1 ^= (n & 7) << 4;
    bf16x8 b0 = *(const bf16x8*)((const char*)wt + byte0);
    bf16x8 b1 = *(const bf16x8*)((const char*)wt + byte1);
    acc[c] = MFMA16(ah0, b0, acc[c]);
    acc[c] = MFMA16(al0, b0, acc[c]);
    acc[c] = MFMA16(ah1, b1, acc[c]);
    acc[c] = MFMA16(al1, b1, acc[c]);
  }
#pragma unroll
  for (int c = 0; c < 16; ++c) {
    float bv = bo[c0 + c * 16 + lr];
#pragma unroll
    for (int j = 0; j < 4; ++j)
      out[(rbase + g * 4 + j) * DM + c0 + c * 16 + lr] = acc[c][j] + bv;
  }
}

// ---------------- host launch ----------------
extern "C" void kernel_launch(void* const* d_in, const int* in_sizes, int n_in,
                              void* d_out, int out_size, void* d_ws,
                              size_t ws_size, hipStream_t stream) {
  const float* q = (const float*)d_in[0];
  const float* k = (const float*)d_in[1];
  const float* v = (const float*)d_in[2];
  const int* mask = (const int*)d_in[3];
  const float* Wq = (const float*)d_in[4];
  const float* bq = (const float*)d_in[5];
  const float* Wk = (const float*)d_in[6];
  const float* bk = (const float*)d_in[7];
  const float* Wv = (const float*)d_in[8];
  const float* bv = (const float*)d_in[9];
  const float* Wo = (const float*)d_in[10];
  const float* bo = (const float*)d_in[11];
  float* out = (float*)d_out;

  // workspace layout (~34 MB)
  bf16_t* qhi = (bf16_t*)d_ws;                         // 2MB
  bf16_t* qlo = qhi + (size_t)NROW * DK;               // 2MB
  char* kimg = (char*)(qlo + (size_t)NROW * DK);       // 4MB  [8][32][16KB]
  char* vimg = kimg + ((size_t)NB * 32 << 14);         // 4MB
  char* wimg = vimg + ((size_t)NB * 32 << 14);         // 768KB [3][16][16KB]
  float* part_acc = (float*)(wimg + (size_t)3 * 16 * 16384);  // 16MB
  float* part_m = part_acc + (size_t)NSPLIT * NROW * DK;
  float* part_l = part_m + (size_t)NSPLIT * NROW;
  float* attn_f = part_l + (size_t)NSPLIT * NROW;  // 4MB
  unsigned int* mbits = (unsigned int*)(attn_f + (size_t)NROW * DK);

  maskpack_kernel<<<dim3(SS * (SS / 32) / 256), dim3(256), 0, stream>>>(mask,
                                                                        mbits);
  wprep_kernel<<<dim3(192), dim3(256), 0, stream>>>(Wq, Wk, Wv, wimg);
  proj3_kernel<<<dim3(NROW / 64, 3), dim3(256), 0, stream>>>(
      q, k, v, wimg, bq, bk, bv, qhi, qlo, kimg, vimg);
  attn_kernel<<<dim3(NROW / 64, NSPLIT), dim3(256), 0, stream>>>(
      qhi, qlo, kimg, vimg, mbits, part_acc, part_m, part_l);
  combine_kernel<<<dim3(NROW * DK / 256), dim3(256), 0, stream>>>(
      part_acc, part_m, part_l, attn_f);
  oproj_kernel<<<dim3(NROW / 64, DM / 256), dim3(256), 0, stream>>>(attn_f, Wo,
                                                                    bo, out);
}

// Round 16
// 150.634 us; speedup vs baseline: 1.0690x; 1.0690x over previous
//
#include <hip/hip_runtime.h>
#include <hip/hip_bf16.h>

typedef __bf16 bf16_t;
typedef __attribute__((ext_vector_type(8))) __bf16 bf16x8;
typedef __attribute__((ext_vector_type(4))) float f32x4;

#define MFMA16(a, b, c) __builtin_amdgcn_mfma_f32_16x16x32_bf16((a), (b), (c), 0, 0, 0)

// Problem sizes
#define NB 8
#define SS 2048
#define DM 1024
#define DK 64
#define NROW (NB * SS)  // 16384
#define NSPLIT 4
#define SPLEN (SS / NSPLIT)  // 512

typedef __attribute__((address_space(1))) const unsigned int ga_u32;
typedef __attribute__((address_space(3))) unsigned int ls_u32;
#define GLOAD16(g, l) \
  __builtin_amdgcn_global_load_lds((ga_u32*)(g), (ls_u32*)(l), 16, 0, 0)

union U16x8 { unsigned short u[8]; uint4 q; };
union U16x4 { unsigned short u[4]; ushort4 v; };

__device__ inline void split_hl(float x, unsigned short& h, unsigned short& l) {
  bf16_t hb = (bf16_t)x;
  bf16_t lb = (bf16_t)(x - (float)hb);
  h = *(unsigned short*)&hb;
  l = *(unsigned short*)&lb;
}

// ---------------- kernel 0: pack mask (int32 0/1) into bits ----------------
__global__ __launch_bounds__(256) void maskpack_kernel(
    const int* __restrict__ mask, unsigned int* __restrict__ mbits) {
  int idx = blockIdx.x * 256 + threadIdx.x;  // word index: q*64 + w
  int q = idx >> 6, w = idx & 63;
  const int4* src = (const int4*)(mask + (q << 11) + (w << 5));
  unsigned int bits = 0u;
#pragma unroll
  for (int i = 0; i < 8; ++i) {
    int4 t = src[i];
    bits |= (t.x != 0 ? 1u : 0u) << (i * 4 + 0);
    bits |= (t.y != 0 ? 1u : 0u) << (i * 4 + 1);
    bits |= (t.z != 0 ? 1u : 0u) << (i * 4 + 2);
    bits |= (t.w != 0 ? 1u : 0u) << (i * 4 + 3);
  }
  mbits[idx] = bits;
}

// ------------- kernel 0b: W -> LDS-ready swizzled tile images ---------------
// wimg layout: [3 modes][16 chunks][16KB]; per chunk: hi 8KB + lo 8KB,
// byte(n, kk) = n*128 + ((2*kk) ^ ((n&7)<<4)),  n=out-col 0..63, kk=k&63.
__global__ __launch_bounds__(256) void wprep_kernel(
    const float* __restrict__ Wq, const float* __restrict__ Wk,
    const float* __restrict__ Wv, char* __restrict__ wimg) {
  int which = blockIdx.x >> 6;
  const float* W = which == 0 ? Wq : (which == 1 ? Wk : Wv);
  char* img = wimg + (size_t)which * 16 * 16384;
  int e = (blockIdx.x & 63) * 256 + threadIdx.x;  // 16384 threads per mode
  int k = e >> 4, n0 = (e & 15) << 2;
  float4 f = *(const float4*)(W + k * 64 + n0);
  float fv[4] = {f.x, f.y, f.z, f.w};
  char* base = img + (k >> 6) * 16384;
  int kk = k & 63;
#pragma unroll
  for (int u = 0; u < 4; ++u) {
    int n = n0 + u;
    unsigned short h, l;
    split_hl(fv[u], h, l);
    int byte = n * 128 + ((2 * kk) ^ ((n & 7) << 4));
    *(unsigned short*)(base + byte) = h;
    *(unsigned short*)(base + 8192 + byte) = l;
  }
}

// ---------------- kernel 1: fused Q/K/V projection (pipelined GEMM) ---------
// Block = 32 rows x 64 cols, 4 waves (wm=wv&1 row-half, wn=wv>>1 col-half).
// LDS 40KB (xbuf 8KB + W dbuf 2x16KB) -> 4 blocks/CU (vs 3 at 64-row).
// Same r11 pipeline: W dbuf via global_load_lds + counted vmcnt(2) (issueX
// is 2 loads now), X one chunk ahead in regs, raw barriers, sched fences.
__global__ __launch_bounds__(256) void proj3_kernel(
    const float* __restrict__ qx, const float* __restrict__ kx,
    const float* __restrict__ vx, const char* __restrict__ wimg,
    const float* __restrict__ bq, const float* __restrict__ bk,
    const float* __restrict__ bv, bf16_t* __restrict__ qhi,
    bf16_t* __restrict__ qlo, char* __restrict__ kimg,
    char* __restrict__ vimg) {
  __shared__ __align__(16) char smem[40960];
  char* xbuf = smem;  // X tile image: hi 4KB + lo 4KB (single-buffered)
  const int mode = blockIdx.y;
  const float* X = mode == 0 ? qx : (mode == 1 ? kx : vx);
  const float* bias = mode == 0 ? bq : (mode == 1 ? bk : bv);
  const int tid = threadIdx.x;
  const int lane = tid & 63;
  const int wv = tid >> 6;
  const int lr = lane & 15;
  const int g = lane >> 4;
  const int wm = wv & 1;   // row half (16 rows)
  const int wn = wv >> 1;  // col half (32 cols)
  const int rbase = blockIdx.x * 32;
  const int xr = tid >> 3;        // staging row 0..31
  const int fo = (tid & 7) * 8;   // staging float-offset in chunk row
  const int row_local = wm * 16 + lr;
  const int swa = (row_local & 7) << 4;
  const int swx = (xr & 7) << 4;

  f32x4 acc[2] = {};
  const char* wsrc0 = wimg + (size_t)mode * 16 * 16384;

  f32x4 xa, xb;  // in-flight X chunk (8 floats)
  auto issueX = [&](int ch) {
    const f32x4* xp =
        (const f32x4*)(X + (size_t)(rbase + xr) * DM + ch * 64 + fo);
    xa = xp[0];
    xb = xp[1];
  };
  auto writeX = [&]() {
    float xv[8] = {xa[0], xa[1], xa[2], xa[3], xb[0], xb[1], xb[2], xb[3]};
    U16x8 hq, lq;
#pragma unroll
    for (int i = 0; i < 8; ++i) split_hl(xv[i], hq.u[i], lq.u[i]);
    char* xh = xbuf + xr * 128;
    int b0 = 2 * fo;
    *(uint4*)(xh + (b0 ^ swx)) = hq.q;
    *(uint4*)(xh + 4096 + (b0 ^ swx)) = lq.q;
  };
  auto stageW = [&](int ch, char* dst) {
    const char* wsrc = wsrc0 + ch * 16384;
#pragma unroll
    for (int u = 0; u < 4; ++u)
      GLOAD16(wsrc + u * 4096 + tid * 16, dst + u * 4096 + tid * 16);
  };
  auto compute = [&](const char* wb) {
#pragma unroll
    for (int ks = 0; ks < 2; ++ks) {
      int co = ks * 64 + g * 16;
      bf16x8 ah = *(const bf16x8*)(xbuf + row_local * 128 + (co ^ swa));
      bf16x8 al = *(const bf16x8*)(xbuf + 4096 + row_local * 128 + (co ^ swa));
#pragma unroll
      for (int c = 0; c < 2; ++c) {
        int n = wn * 32 + c * 16 + lr;
        int swb = (n & 7) << 4;
        bf16x8 bh = *(const bf16x8*)(wb + n * 128 + (co ^ swb));
        bf16x8 bl = *(const bf16x8*)(wb + 8192 + n * 128 + (co ^ swb));
        acc[c] = MFMA16(ah, bl, acc[c]);
        acc[c] = MFMA16(al, bh, acc[c]);
        acc[c] = MFMA16(ah, bh, acc[c]);
      }
    }
  };

  // ---- prologue: fill X(0)+W(0), leave X(1) in flight ----
  issueX(0);
  __builtin_amdgcn_sched_barrier(0);
  stageW(0, smem + 8192);
  __builtin_amdgcn_sched_barrier(0);
  writeX();     // compiler inserts the wait for X(0)
  issueX(1);    // X(1) in flight (2 newer than W(0)'s 4)
  __builtin_amdgcn_sched_barrier(0);
  asm volatile("s_waitcnt vmcnt(2)" ::: "memory");   // W(0) landed
  asm volatile("s_waitcnt lgkmcnt(0)" ::: "memory"); // xbuf writes done
  __builtin_amdgcn_s_barrier();
  __builtin_amdgcn_sched_barrier(0);

  for (int ch = 0; ch < 16; ++ch) {
    char* wc = (ch & 1) ? smem + 24576 : smem + 8192;
    char* wn_ = (ch & 1) ? smem + 8192 : smem + 24576;
    if (ch < 15) stageW(ch + 1, wn_);  // issue next W before compute
    compute(wc);
    if (ch < 15) {
      __builtin_amdgcn_sched_barrier(0);
      __builtin_amdgcn_s_barrier();  // all waves done reading xbuf
      __builtin_amdgcn_sched_barrier(0);
      writeX();  // X(ch+1) regs -> xbuf (compiler waits the X loads)
      if (ch < 14) {
        issueX(ch + 2);
        __builtin_amdgcn_sched_barrier(0);
        // outstanding: W(ch+1)=4 older, X(ch+2)=2 newer -> wait W done
        asm volatile("s_waitcnt vmcnt(2)" ::: "memory");
      } else {
        asm volatile("s_waitcnt vmcnt(0)" ::: "memory");
      }
      asm volatile("s_waitcnt lgkmcnt(0)" ::: "memory");
      __builtin_amdgcn_s_barrier();
      __builtin_amdgcn_sched_barrier(0);
    }
  }
  // ---- epilogue: stage acc to LDS [32][69] fp32, then mode-specific emit ---
  __syncthreads();
  float* sacc = (float*)smem;
#pragma unroll
  for (int c = 0; c < 2; ++c)
#pragma unroll
    for (int j = 0; j < 4; ++j)
      sacc[(wm * 16 + g * 4 + j) * 69 + wn * 32 + c * 16 + lr] = acc[c][j];
  __syncthreads();

  const int b = rbase >> 11;
  const int t = (rbase & (SS - 1)) >> 6;  // 64-row tile index
  const int rt0 = rbase & 63;             // 0 or 32 within tile
  if (mode == 0) {
    int r = tid & 31, cg = tid >> 5;  // 8 col-groups of 8
    int row = rbase + r;
    U16x8 h, l;
#pragma unroll
    for (int i = 0; i < 8; ++i) {
      float v = sacc[r * 69 + cg * 8 + i] + bias[cg * 8 + i];
      split_hl(v, h.u[i], l.u[i]);
    }
    *(uint4*)((char*)qhi + (size_t)row * 128 + cg * 16) = h.q;
    *(uint4*)((char*)qlo + (size_t)row * 128 + cg * 16) = l.q;
  } else if (mode == 1) {
    int r = tid & 31, cg = tid >> 5;
    int rr = rt0 + r;
    char* base = kimg + (((size_t)(b * 32 + t)) << 14);
    int off = rr * 128 + ((cg * 16) ^ ((rr & 7) << 4));
    U16x8 h, l;
#pragma unroll
    for (int i = 0; i < 8; ++i) {
      float v = sacc[r * 69 + cg * 8 + i] + bias[cg * 8 + i];
      split_hl(v, h.u[i], l.u[i]);
    }
    *(uint4*)(base + off) = h.q;
    *(uint4*)(base + 8192 + off) = l.q;
  } else {
    int d = tid & 63, rg = tid >> 6;  // 4 key-groups of 8
    char* base = vimg + (((size_t)(b * 32 + t)) << 14);
    float bv = bias[d];
    U16x8 h, l;
#pragma unroll
    for (int i = 0; i < 8; ++i) {
      float v = sacc[(rg * 8 + i) * 69 + d] + bv;
      split_hl(v, h.u[i], l.u[i]);
    }
    int off = d * 128 + (((rt0 + rg * 8) * 2) ^ ((d & 7) << 4));
    *(uint4*)(base + off) = h.q;
    *(uint4*)(base + 8192 + off) = l.q;
  }
}

// ---------------- kernel 2: flash attention (split-KV, LDS-shared) --------
__global__ __launch_bounds__(256) void attn_kernel(
    const bf16_t* __restrict__ qhi, const bf16_t* __restrict__ qlo,
    const char* __restrict__ kimg, const char* __restrict__ vimg,
    const unsigned int* __restrict__ mbits, float* __restrict__ part_acc,
    float* __restrict__ part_m, float* __restrict__ part_l) {
  __shared__ __align__(16) char kbuf[16384];
  __shared__ __align__(16) char vbuf[16384];
  __shared__ __align__(16) char plds_all[4][2048];
  const int tid = threadIdx.x;
  const int lane = tid & 63;
  const int wv = tid >> 6;
  const int lr = lane & 15;
  const int g = lane >> 4;
  char* plds = &plds_all[wv][0];
  const int qrow0 = (blockIdx.x * 4 + wv) * 16;
  const int split = blockIdx.y;
  const int kv0 = split * SPLEN;
  const int b = qrow0 >> 11;
  const int sq0 = (qrow0 & (SS - 1)) + g * 4;  // mask row base (per j)

  const bf16_t* qh = qhi + (qrow0 + lr) * DK + g * 8;
  const bf16_t* ql = qlo + (qrow0 + lr) * DK + g * 8;
  bf16x8 qh0 = *(const bf16x8*)qh;
  bf16x8 qh1 = *(const bf16x8*)(qh + 32);
  bf16x8 ql0 = *(const bf16x8*)ql;
  bf16x8 ql1 = *(const bf16x8*)(ql + 32);

  float m[4], lsum[4];
  f32x4 acc[4] = {};
#pragma unroll
  for (int j = 0; j < 4; ++j) { m[j] = -3.0e38f; lsum[j] = 0.f; }

  for (int it = 0; it < SPLEN / 64; ++it) {
    const int tglob = (kv0 >> 6) + it;
    const char* ksrc = kimg + (((size_t)(b * 32 + tglob)) << 14);
    const char* vsrc = vimg + (((size_t)(b * 32 + tglob)) << 14);
#pragma unroll
    for (int u = 0; u < 4; ++u) {
      GLOAD16(ksrc + tid * 16 + u * 4096, kbuf + tid * 16 + u * 4096);
      GLOAD16(vsrc + tid * 16 + u * 4096, vbuf + tid * 16 + u * 4096);
    }
    asm volatile("s_waitcnt vmcnt(0)\n" ::: "memory");
    __syncthreads();
    // QK^T over 64-key tile
    f32x4 sac[4];
#pragma unroll
    for (int t = 0; t < 4; ++t) {
      int rk = t * 16 + lr;
      int sw = (rk & 7) << 4;
      bf16x8 kh0 = *(const bf16x8*)(kbuf + rk * 128 + ((g * 16) ^ sw));
      bf16x8 kh1 = *(const bf16x8*)(kbuf + rk * 128 + ((64 + g * 16) ^ sw));
      bf16x8 kl0 = *(const bf16x8*)(kbuf + 8192 + rk * 128 + ((g * 16) ^ sw));
      bf16x8 kl1 =
          *(const bf16x8*)(kbuf + 8192 + rk * 128 + ((64 + g * 16) ^ sw));
      f32x4 s = {};
      s = MFMA16(qh0, kl0, s);
      s = MFMA16(qh1, kl1, s);
      s = MFMA16(ql0, kh0, s);
      s = MFMA16(ql1, kh1, s);
      s = MFMA16(qh0, kh0, s);
      s = MFMA16(qh1, kh1, s);
      sac[t] = s;
    }
    // mask: 2 words per row cover this 64-key tile
    const int wbase = (kv0 >> 5) + it * 2;
    uint2 m2[4];
#pragma unroll
    for (int j = 0; j < 4; ++j)
      m2[j] = *(const uint2*)(mbits + (sq0 + j) * 64 + wbase);
#pragma unroll
    for (int t = 0; t < 4; ++t)
#pragma unroll
      for (int j = 0; j < 4; ++j) {
        unsigned w = (t & 2) ? m2[j].y : m2[j].x;
        if (!((w >> ((t & 1) * 16 + lr)) & 1u)) sac[t][j] = -1e9f;
      }
    // online softmax
#pragma unroll
    for (int j = 0; j < 4; ++j) {
      float v = sac[0][j];
#pragma unroll
      for (int t = 1; t < 4; ++t) v = fmaxf(v, sac[t][j]);
      v = fmaxf(v, __shfl_xor(v, 1, 64));
      v = fmaxf(v, __shfl_xor(v, 2, 64));
      v = fmaxf(v, __shfl_xor(v, 4, 64));
      v = fmaxf(v, __shfl_xor(v, 8, 64));
      float mn = fmaxf(m[j], v);
      float sc = __expf(m[j] - mn);
      m[j] = mn;
      lsum[j] *= sc;
#pragma unroll
      for (int c = 0; c < 4; ++c) acc[c][j] *= sc;
    }
    // P = exp(s - m) -> wave-private swizzled LDS
    float ps[4] = {0.f, 0.f, 0.f, 0.f};
#pragma unroll
    for (int t = 0; t < 4; ++t)
#pragma unroll
      for (int j = 0; j < 4; ++j) {
        float p = __expf(sac[t][j] - m[j]);
        bf16_t pb = (bf16_t)p;
        ps[j] += (float)pb;  // lsum over ROUNDED p -> exact convex combo
        int row = g * 4 + j;
        int byte = row * 128 + (((t * 16 + lr) * 2) ^ ((row & 7) << 4));
        *(bf16_t*)(plds + byte) = pb;
      }
#pragma unroll
    for (int j = 0; j < 4; ++j) {
      float s_ = ps[j];
      s_ += __shfl_xor(s_, 1, 64);
      s_ += __shfl_xor(s_, 2, 64);
      s_ += __shfl_xor(s_, 4, 64);
      s_ += __shfl_xor(s_, 8, 64);
      lsum[j] += s_;
    }
    asm volatile("s_waitcnt lgkmcnt(0)\n" ::: "memory");
    // PV: A = P (transposed LDS read), B = V hi + lo from vbuf
#pragma unroll
    for (int kt = 0; kt < 2; ++kt) {
      int pbyte = lr * 128 + ((kt * 64 + g * 16) ^ ((lr & 7) << 4));
      bf16x8 pa = *(const bf16x8*)(plds + pbyte);
#pragma unroll
      for (int c = 0; c < 4; ++c) {
        int n = c * 16 + lr;
        int swv = (n & 7) << 4;
        bf16x8 vfh = *(const bf16x8*)(vbuf + n * 128 + ((kt * 64 + g * 16) ^ swv));
        bf16x8 vfl =
            *(const bf16x8*)(vbuf + 8192 + n * 128 + ((kt * 64 + g * 16) ^ swv));
        acc[c] = MFMA16(pa, vfh, acc[c]);
        acc[c] = MFMA16(pa, vfl, acc[c]);
      }
    }
    __syncthreads();  // all waves done reading kbuf/vbuf before next stage
  }
  // epilogue: write unnormalized partials
#pragma unroll
  for (int c = 0; c < 4; ++c)
#pragma unroll
    for (int j = 0; j < 4; ++j)
      part_acc[((size_t)split * NROW + qrow0 + g * 4 + j) * DK + c * 16 + lr] =
          acc[c][j];
  if (lr == 0) {
#pragma unroll
    for (int j = 0; j < 4; ++j) {
      part_m[split * NROW + qrow0 + g * 4 + j] = m[j];
      part_l[split * NROW + qrow0 + g * 4 + j] = lsum[j];
    }
  }
}

// ---------------- kernel 2b: combine split-KV partials ----------------
__global__ __launch_bounds__(256) void combine_kernel(
    const float* __restrict__ pacc, const float* __restrict__ pm,
    const float* __restrict__ pl, float* __restrict__ attn_f) {
  int idx = blockIdx.x * 256 + threadIdx.x;
  int row = idx >> 6;
  float m0 = pm[row], m1 = pm[NROW + row];
  float m2 = pm[2 * NROW + row], m3 = pm[3 * NROW + row];
  float M = fmaxf(fmaxf(m0, m1), fmaxf(m2, m3));
  float w0 = __expf(m0 - M), w1 = __expf(m1 - M);
  float w2 = __expf(m2 - M), w3 = __expf(m3 - M);
  float l = w0 * pl[row] + w1 * pl[NROW + row] + w2 * pl[2 * NROW + row] +
            w3 * pl[3 * NROW + row];
  float a = w0 * pacc[idx] + w1 * pacc[(size_t)NROW * DK + idx] +
            w2 * pacc[2 * (size_t)NROW * DK + idx] +
            w3 * pacc[3 * (size_t)NROW * DK + idx];
  attn_f[idx] = a / l;
}

// ---------------- kernel 3: output projection  out = A @ Wo + bo ----------
__global__ __launch_bounds__(256) void oproj_kernel(
    const float* __restrict__ attn, const float* __restrict__ Wo,
    const float* __restrict__ bo, float* __restrict__ out) {
  __shared__ __align__(16) bf16_t wt[256 * 64];  // Wo^T chunk [n][k], swizzled
  const int tid = threadIdx.x;
  const int lane = tid & 63;
  const int wv = tid >> 6;
  const int lr = lane & 15;
  const int g = lane >> 4;
  const int rbase = blockIdx.x * 64 + wv * 16;
  const int c0 = blockIdx.y * 256;
  {  // stage Wo[0..64][c0..c0+256] -> wt[n][k]
    const int k = tid >> 2;
    const int n0 = (tid & 3) << 6;
    const float4* src = (const float4*)(Wo + k * DM + c0 + n0);
#pragma unroll
    for (int i = 0; i < 16; ++i) {
      float4 f = src[i];
      float fv[4] = {f.x, f.y, f.z, f.w};
#pragma unroll
      for (int u = 0; u < 4; ++u) {
        int n = n0 + i * 4 + u;
        int byte = (n << 7) + (k << 1);
        byte ^= (n & 7) << 4;
        *(bf16_t*)((char*)wt + byte) = (bf16_t)fv[u];
      }
    }
  }
  __syncthreads();
  const float* ab = attn + (rbase + lr) * DK + g * 8;
  float4 x0 = *(const float4*)ab;
  float4 x1 = *(const float4*)(ab + 4);
  float4 y0 = *(const float4*)(ab + 32);
  float4 y1 = *(const float4*)(ab + 36);
  float xv[8] = {x0.x, x0.y, x0.z, x0.w, x1.x, x1.y, x1.z, x1.w};
  float yv[8] = {y0.x, y0.y, y0.z, y0.w, y1.x, y1.y, y1.z, y1.w};
  bf16x8 ah0, al0, ah1, al1;
#pragma unroll
  for (int i = 0; i < 8; ++i) {
    ah0[i] = (bf16_t)xv[i];
    al0[i] = (bf16_t)(xv[i] - (float)ah0[i]);
    ah1[i] = (bf16_t)yv[i];
    al1[i] = (bf16_t)(yv[i] - (float)ah1[i]);
  }
  f32x4 acc[16] = {};
#pragma unroll
  for (int c = 0; c < 16; ++c) {
    int n = c * 16 + lr;
    int byte0 = (n << 7) + ((g * 8) << 1);
    byte0 ^= (n & 7) << 4;
    int byte1 = (n << 7) + ((32 + g * 8) << 1);
    byte1 ^= (n & 7) << 4;
    bf16x8 b0 = *(const bf16x8*)((const char*)wt + byte0);
    bf16x8 b1 = *(const bf16x8*)((const char*)wt + byte1);
    acc[c] = MFMA16(ah0, b0, acc[c]);
    acc[c] = MFMA16(al0, b0, acc[c]);
    acc[c] = MFMA16(ah1, b1, acc[c]);
    acc[c] = MFMA16(al1, b1, acc[c]);
  }
#pragma unroll
  for (int c = 0; c < 16; ++c) {
    float bv = bo[c0 + c * 16 + lr];
#pragma unroll
    for (int j = 0; j < 4; ++j)
      out[(rbase + g * 4 + j) * DM + c0 + c * 16 + lr] = acc[c][j] + bv;
  }
}

// ---------------- host launch ----------------
extern "C" void kernel_launch(void* const* d_in, const int* in_sizes, int n_in,
                              void* d_out, int out_size, void* d_ws,
                              size_t ws_size, hipStream_t stream) {
  const float* q = (const float*)d_in[0];
  const float* k = (const float*)d_in[1];
  const float* v = (const float*)d_in[2];
  const int* mask = (const int*)d_in[3];
  const float* Wq = (const float*)d_in[4];
  const float* bq = (const float*)d_in[5];
  const float* Wk = (const float*)d_in[6];
  const float* bk = (const float*)d_in[7];
  const float* Wv = (const float*)d_in[8];
  const float* bv = (const float*)d_in[9];
  const float* Wo = (const float*)d_in[10];
  const float* bo = (const float*)d_in[11];
  float* out = (float*)d_out;

  // workspace layout (~34 MB)
  bf16_t* qhi = (bf16_t*)d_ws;                         // 2MB
  bf16_t* qlo = qhi + (size_t)NROW * DK;               // 2MB
  char* kimg = (char*)(qlo + (size_t)NROW * DK);       // 4MB  [8][32][16KB]
  char* vimg = kimg + ((size_t)NB * 32 << 14);         // 4MB
  char* wimg = vimg + ((size_t)NB * 32 << 14);         // 768KB [3][16][16KB]
  float* part_acc = (float*)(wimg + (size_t)3 * 16 * 16384);  // 16MB
  float* part_m = part_acc + (size_t)NSPLIT * NROW * DK;
  float* part_l = part_m + (size_t)NSPLIT * NROW;
  float* attn_f = part_l + (size_t)NSPLIT * NROW;  // 4MB
  unsigned int* mbits = (unsigned int*)(attn_f + (size_t)NROW * DK);

  maskpack_kernel<<<dim3(SS * (SS / 32) / 256), dim3(256), 0, stream>>>(mask,
                                                                        mbits);
  wprep_kernel<<<dim3(192), dim3(256), 0, stream>>>(Wq, Wk, Wv, wimg);
  proj3_kernel<<<dim3(NROW / 32, 3), dim3(256), 0, stream>>>(
      q, k, v, wimg, bq, bk, bv, qhi, qlo, kimg, vimg);
  attn_kernel<<<dim3(NROW / 64, NSPLIT), dim3(256), 0, stream>>>(
      qhi, qlo, kimg, vimg, mbits, part_acc, part_m, part_l);
  combine_kernel<<<dim3(NROW * DK / 256), dim3(256), 0, stream>>>(
      part_acc, part_m, part_l, attn_f);
  oproj_kernel<<<dim3(NROW / 64, DM / 256), dim3(256), 0, stream>>>(attn_f, Wo,
                                                                    bo, out);
}

// Round 17
// 139.817 us; speedup vs baseline: 1.1517x; 1.0774x over previous
//
#include <hip/hip_runtime.h>
#include <hip/hip_bf16.h>

typedef __bf16 bf16_t;
typedef __attribute__((ext_vector_type(8))) __bf16 bf16x8;
typedef __attribute__((ext_vector_type(4))) float f32x4;

#define MFMA16(a, b, c) __builtin_amdgcn_mfma_f32_16x16x32_bf16((a), (b), (c), 0, 0, 0)

// Problem sizes
#define NB 8
#define SS 2048
#define DM 1024
#define DK 64
#define NROW (NB * SS)  // 16384
#define NSPLIT 4
#define SPLEN (SS / NSPLIT)  // 512

typedef __attribute__((address_space(1))) const unsigned int ga_u32;
typedef __attribute__((address_space(3))) unsigned int ls_u32;
#define GLOAD16(g, l) \
  __builtin_amdgcn_global_load_lds((ga_u32*)(g), (ls_u32*)(l), 16, 0, 0)

union U16x8 { unsigned short u[8]; uint4 q; };
union U16x4 { unsigned short u[4]; ushort4 v; };

__device__ inline void split_hl(float x, unsigned short& h, unsigned short& l) {
  bf16_t hb = (bf16_t)x;
  bf16_t lb = (bf16_t)(x - (float)hb);
  h = *(unsigned short*)&hb;
  l = *(unsigned short*)&lb;
}

// ---------------- kernel 0: pack mask (int32 0/1) into bits ----------------
__global__ __launch_bounds__(256) void maskpack_kernel(
    const int* __restrict__ mask, unsigned int* __restrict__ mbits) {
  int idx = blockIdx.x * 256 + threadIdx.x;  // word index: q*64 + w
  int q = idx >> 6, w = idx & 63;
  const int4* src = (const int4*)(mask + (q << 11) + (w << 5));
  unsigned int bits = 0u;
#pragma unroll
  for (int i = 0; i < 8; ++i) {
    int4 t = src[i];
    bits |= (t.x != 0 ? 1u : 0u) << (i * 4 + 0);
    bits |= (t.y != 0 ? 1u : 0u) << (i * 4 + 1);
    bits |= (t.z != 0 ? 1u : 0u) << (i * 4 + 2);
    bits |= (t.w != 0 ? 1u : 0u) << (i * 4 + 3);
  }
  mbits[idx] = bits;
}

// ------------- kernel 0b: W -> LDS-ready swizzled tile images ---------------
// wimg layout: [3 modes][16 chunks][16KB]; per chunk: hi 8KB + lo 8KB,
// byte(n, kk) = n*128 + ((2*kk) ^ ((n&7)<<4)),  n=out-col 0..63, kk=k&63.
__global__ __launch_bounds__(256) void wprep_kernel(
    const float* __restrict__ Wq, const float* __restrict__ Wk,
    const float* __restrict__ Wv, char* __restrict__ wimg) {
  int which = blockIdx.x >> 6;
  const float* W = which == 0 ? Wq : (which == 1 ? Wk : Wv);
  char* img = wimg + (size_t)which * 16 * 16384;
  int e = (blockIdx.x & 63) * 256 + threadIdx.x;  // 16384 threads per mode
  int k = e >> 4, n0 = (e & 15) << 2;
  float4 f = *(const float4*)(W + k * 64 + n0);
  float fv[4] = {f.x, f.y, f.z, f.w};
  char* base = img + (k >> 6) * 16384;
  int kk = k & 63;
#pragma unroll
  for (int u = 0; u < 4; ++u) {
    int n = n0 + u;
    unsigned short h, l;
    split_hl(fv[u], h, l);
    int byte = n * 128 + ((2 * kk) ^ ((n & 7) << 4));
    *(unsigned short*)(base + byte) = h;
    *(unsigned short*)(base + 8192 + byte) = l;
  }
}

// ---------------- kernel 1: fused Q/K/V projection (pipelined GEMM) ---------
// Block = 64 rows x 64 cols, 4 waves. K-chunks of 64, software-pipelined:
//  - W chunk images double-buffered via global_load_lds, counted vmcnt(4)
//  - X chunk prefetched to registers one chunk ahead (issue-early/write-late)
//  - raw s_barrier + manual lgkmcnt so prefetches stay in flight
__global__ __launch_bounds__(256) void proj3_kernel(
    const float* __restrict__ qx, const float* __restrict__ kx,
    const float* __restrict__ vx, const char* __restrict__ wimg,
    const float* __restrict__ bq, const float* __restrict__ bk,
    const float* __restrict__ bv, bf16_t* __restrict__ qhi,
    bf16_t* __restrict__ qlo, char* __restrict__ kimg,
    char* __restrict__ vimg) {
  __shared__ __align__(16) char smem[49152];
  char* xbuf = smem;  // X tile image: hi 8KB + lo 8KB (single-buffered)
  const int mode = blockIdx.y;
  const float* X = mode == 0 ? qx : (mode == 1 ? kx : vx);
  const float* bias = mode == 0 ? bq : (mode == 1 ? bk : bv);
  const int tid = threadIdx.x;
  const int lane = tid & 63;
  const int wv = tid >> 6;
  const int lr = lane & 15;
  const int g = lane >> 4;
  const int rbase = blockIdx.x * 64;
  const int xr = tid >> 2;             // staging row 0..63
  const int kg = (tid & 3) << 4;       // staging k-offset (floats)
  const int row_local = wv * 16 + lr;  // compute A row
  const int swa = (row_local & 7) << 4;
  const int swx = (xr & 7) << 4;

  f32x4 acc[4] = {};
  const char* wsrc0 = wimg + (size_t)mode * 16 * 16384;

  float4 xa, xb, xc, xd;  // in-flight X chunk (16 floats)
  auto issueX = [&](int ch) {
    const float4* xp =
        (const float4*)(X + (size_t)(rbase + xr) * DM + ch * 64 + kg);
    xa = xp[0]; xb = xp[1]; xc = xp[2]; xd = xp[3];
  };
  auto writeX = [&]() {
    float xv[16] = {xa.x, xa.y, xa.z, xa.w, xb.x, xb.y, xb.z, xb.w,
                    xc.x, xc.y, xc.z, xc.w, xd.x, xd.y, xd.z, xd.w};
    U16x8 hq[2], lq[2];
#pragma unroll
    for (int i = 0; i < 16; ++i)
      split_hl(xv[i], hq[i >> 3].u[i & 7], lq[i >> 3].u[i & 7]);
    char* xh = xbuf + xr * 128;
    int b0 = 2 * kg;
    *(uint4*)(xh + (b0 ^ swx)) = hq[0].q;
    *(uint4*)(xh + ((b0 + 16) ^ swx)) = hq[1].q;
    *(uint4*)(xh + 8192 + (b0 ^ swx)) = lq[0].q;
    *(uint4*)(xh + 8192 + ((b0 + 16) ^ swx)) = lq[1].q;
  };
  auto stageW = [&](int ch, char* dst) {
    const char* wsrc = wsrc0 + ch * 16384;
#pragma unroll
    for (int u = 0; u < 4; ++u)
      GLOAD16(wsrc + u * 4096 + tid * 16, dst + u * 4096 + tid * 16);
  };
  auto compute = [&](const char* wb) {
#pragma unroll
    for (int ks = 0; ks < 2; ++ks) {
      int co = ks * 64 + g * 16;
      bf16x8 ah = *(const bf16x8*)(xbuf + row_local * 128 + (co ^ swa));
      bf16x8 al = *(const bf16x8*)(xbuf + 8192 + row_local * 128 + (co ^ swa));
#pragma unroll
      for (int c = 0; c < 4; ++c) {
        int n = c * 16 + lr;
        int swb = (n & 7) << 4;
        bf16x8 bh = *(const bf16x8*)(wb + n * 128 + (co ^ swb));
        bf16x8 bl = *(const bf16x8*)(wb + 8192 + n * 128 + (co ^ swb));
        acc[c] = MFMA16(ah, bl, acc[c]);
        acc[c] = MFMA16(al, bh, acc[c]);
        acc[c] = MFMA16(ah, bh, acc[c]);
      }
    }
  };

  // ---- prologue: fill X(0)+W(0), leave X(1)+nothing in flight ----
  issueX(0);
  stageW(0, smem + 16384);
  writeX();     // compiler inserts the wait for X(0)
  issueX(1);    // X(1) in flight (4 newer than W(0)'s 4)
  asm volatile("s_waitcnt vmcnt(4)" ::: "memory");   // W(0) landed
  asm volatile("s_waitcnt lgkmcnt(0)" ::: "memory"); // xbuf writes done
  __builtin_amdgcn_s_barrier();
  __builtin_amdgcn_sched_barrier(0);

  for (int ch = 0; ch < 16; ++ch) {
    char* wc = (ch & 1) ? smem + 32768 : smem + 16384;
    char* wn = (ch & 1) ? smem + 16384 : smem + 32768;
    if (ch < 15) stageW(ch + 1, wn);  // issue next W before compute
    compute(wc);
    if (ch < 15) {
      __builtin_amdgcn_sched_barrier(0);
      __builtin_amdgcn_s_barrier();  // all waves done reading xbuf
      __builtin_amdgcn_sched_barrier(0);
      writeX();  // X(ch+1) regs -> xbuf (compiler waits the X loads)
      if (ch < 14) {
        issueX(ch + 2);
        // outstanding: W(ch+1)=4 older, X(ch+2)=4 newer -> wait W done
        asm volatile("s_waitcnt vmcnt(4)" ::: "memory");
      } else {
        asm volatile("s_waitcnt vmcnt(0)" ::: "memory");
      }
      asm volatile("s_waitcnt lgkmcnt(0)" ::: "memory");
      __builtin_amdgcn_s_barrier();
      __builtin_amdgcn_sched_barrier(0);
    }
  }
  // ---- epilogue: stage acc to LDS [64][69] fp32, then mode-specific emit ---
  __syncthreads();
  float* sacc = (float*)smem;
#pragma unroll
  for (int c = 0; c < 4; ++c)
#pragma unroll
    for (int j = 0; j < 4; ++j)
      sacc[(wv * 16 + g * 4 + j) * 69 + c * 16 + lr] = acc[c][j];
  __syncthreads();

  const int b = rbase >> 11;
  const int t = (rbase & (SS - 1)) >> 6;
  if (mode == 0) {
    int r = tid & 63, cg = tid >> 6;
    int row = rbase + r;
    U16x8 h0, h1, l0, l1;
#pragma unroll
    for (int i = 0; i < 16; ++i) {
      float v = sacc[r * 69 + cg * 16 + i] + bias[cg * 16 + i];
      if (i < 8) split_hl(v, h0.u[i & 7], l0.u[i & 7]);
      else       split_hl(v, h1.u[i & 7], l1.u[i & 7]);
    }
    *(uint4*)((char*)qhi + (size_t)row * 128 + cg * 32) = h0.q;
    *(uint4*)((char*)qhi + (size_t)row * 128 + cg * 32 + 16) = h1.q;
    *(uint4*)((char*)qlo + (size_t)row * 128 + cg * 32) = l0.q;
    *(uint4*)((char*)qlo + (size_t)row * 128 + cg * 32 + 16) = l1.q;
  } else if (mode == 1) {
    int r = tid & 63, cg = tid >> 6;
    char* base = kimg + (((size_t)(b * 32 + t)) << 14);
    int sw = (r & 7) << 4;
#pragma unroll
    for (int m = 0; m < 4; ++m) {
      U16x4 hv, lv;
#pragma unroll
      for (int u = 0; u < 4; ++u) {
        int col = cg * 16 + m * 4 + u;
        float v = sacc[r * 69 + col] + bias[col];
        split_hl(v, hv.u[u], lv.u[u]);
      }
      int off = (cg * 32 + m * 8) ^ sw;
      *(ushort4*)(base + r * 128 + off) = hv.v;
      *(ushort4*)(base + 8192 + r * 128 + off) = lv.v;
    }
  } else {
    int d = tid & 63, rg = tid >> 6;
    char* base = vimg + (((size_t)(b * 32 + t)) << 14);
    int sw = (d & 7) << 4;
    float bv = bias[d];
#pragma unroll
    for (int m = 0; m < 4; ++m) {
      U16x4 hv, lv;
#pragma unroll
      for (int u = 0; u < 4; ++u) {
        int r = rg * 16 + m * 4 + u;
        float v = sacc[r * 69 + d] + bv;
        split_hl(v, hv.u[u], lv.u[u]);
      }
      int off = (rg * 32 + m * 8) ^ sw;
      *(ushort4*)(base + d * 128 + off) = hv.v;
      *(ushort4*)(base + 8192 + d * 128 + off) = lv.v;
    }
  }
}

// ---------------- kernel 2: flash attention (split-KV, LDS-shared) --------
__global__ __launch_bounds__(256) void attn_kernel(
    const bf16_t* __restrict__ qhi, const bf16_t* __restrict__ qlo,
    const char* __restrict__ kimg, const char* __restrict__ vimg,
    const unsigned int* __restrict__ mbits, float* __restrict__ part_acc,
    float* __restrict__ part_m, float* __restrict__ part_l) {
  __shared__ __align__(16) char kbuf[16384];
  __shared__ __align__(16) char vbuf[16384];
  __shared__ __align__(16) char plds_all[4][2048];
  const int tid = threadIdx.x;
  const int lane = tid & 63;
  const int wv = tid >> 6;
  const int lr = lane & 15;
  const int g = lane >> 4;
  char* plds = &plds_all[wv][0];
  const int qrow0 = (blockIdx.x * 4 + wv) * 16;
  const int split = blockIdx.y;
  const int kv0 = split * SPLEN;
  const int b = qrow0 >> 11;
  const int sq0 = (qrow0 & (SS - 1)) + g * 4;  // mask row base (per j)

  const bf16_t* qh = qhi + (qrow0 + lr) * DK + g * 8;
  const bf16_t* ql = qlo + (qrow0 + lr) * DK + g * 8;
  bf16x8 qh0 = *(const bf16x8*)qh;
  bf16x8 qh1 = *(const bf16x8*)(qh + 32);
  bf16x8 ql0 = *(const bf16x8*)ql;
  bf16x8 ql1 = *(const bf16x8*)(ql + 32);

  float m[4], lsum[4];
  f32x4 acc[4] = {};
#pragma unroll
  for (int j = 0; j < 4; ++j) { m[j] = -3.0e38f; lsum[j] = 0.f; }

  for (int it = 0; it < SPLEN / 64; ++it) {
    const int tglob = (kv0 >> 6) + it;
    const char* ksrc = kimg + (((size_t)(b * 32 + tglob)) << 14);
    const char* vsrc = vimg + (((size_t)(b * 32 + tglob)) << 14);
#pragma unroll
    for (int u = 0; u < 4; ++u) {
      GLOAD16(ksrc + tid * 16 + u * 4096, kbuf + tid * 16 + u * 4096);
      GLOAD16(vsrc + tid * 16 + u * 4096, vbuf + tid * 16 + u * 4096);
    }
    asm volatile("s_waitcnt vmcnt(0)\n" ::: "memory");
    __syncthreads();
    // QK^T over 64-key tile
    f32x4 sac[4];
#pragma unroll
    for (int t = 0; t < 4; ++t) {
      int rk = t * 16 + lr;
      int sw = (rk & 7) << 4;
      bf16x8 kh0 = *(const bf16x8*)(kbuf + rk * 128 + ((g * 16) ^ sw));
      bf16x8 kh1 = *(const bf16x8*)(kbuf + rk * 128 + ((64 + g * 16) ^ sw));
      bf16x8 kl0 = *(const bf16x8*)(kbuf + 8192 + rk * 128 + ((g * 16) ^ sw));
      bf16x8 kl1 =
          *(const bf16x8*)(kbuf + 8192 + rk * 128 + ((64 + g * 16) ^ sw));
      f32x4 s = {};
      s = MFMA16(qh0, kl0, s);
      s = MFMA16(qh1, kl1, s);
      s = MFMA16(ql0, kh0, s);
      s = MFMA16(ql1, kh1, s);
      s = MFMA16(qh0, kh0, s);
      s = MFMA16(qh1, kh1, s);
      sac[t] = s;
    }
    // mask: 2 words per row cover this 64-key tile
    const int wbase = (kv0 >> 5) + it * 2;
    uint2 m2[4];
#pragma unroll
    for (int j = 0; j < 4; ++j)
      m2[j] = *(const uint2*)(mbits + (sq0 + j) * 64 + wbase);
#pragma unroll
    for (int t = 0; t < 4; ++t)
#pragma unroll
      for (int j = 0; j < 4; ++j) {
        unsigned w = (t & 2) ? m2[j].y : m2[j].x;
        if (!((w >> ((t & 1) * 16 + lr)) & 1u)) sac[t][j] = -1e9f;
      }
    // online softmax
#pragma unroll
    for (int j = 0; j < 4; ++j) {
      float v = sac[0][j];
#pragma unroll
      for (int t = 1; t < 4; ++t) v = fmaxf(v, sac[t][j]);
      v = fmaxf(v, __shfl_xor(v, 1, 64));
      v = fmaxf(v, __shfl_xor(v, 2, 64));
      v = fmaxf(v, __shfl_xor(v, 4, 64));
      v = fmaxf(v, __shfl_xor(v, 8, 64));
      float mn = fmaxf(m[j], v);
      float sc = __expf(m[j] - mn);
      m[j] = mn;
      lsum[j] *= sc;
#pragma unroll
      for (int c = 0; c < 4; ++c) acc[c][j] *= sc;
    }
    // P = exp(s - m) -> wave-private swizzled LDS
    float ps[4] = {0.f, 0.f, 0.f, 0.f};
#pragma unroll
    for (int t = 0; t < 4; ++t)
#pragma unroll
      for (int j = 0; j < 4; ++j) {
        float p = __expf(sac[t][j] - m[j]);
        bf16_t pb = (bf16_t)p;
        ps[j] += (float)pb;  // lsum over ROUNDED p -> exact convex combo
        int row = g * 4 + j;
        int byte = row * 128 + (((t * 16 + lr) * 2) ^ ((row & 7) << 4));
        *(bf16_t*)(plds + byte) = pb;
      }
#pragma unroll
    for (int j = 0; j < 4; ++j) {
      float s_ = ps[j];
      s_ += __shfl_xor(s_, 1, 64);
      s_ += __shfl_xor(s_, 2, 64);
      s_ += __shfl_xor(s_, 4, 64);
      s_ += __shfl_xor(s_, 8, 64);
      lsum[j] += s_;
    }
    asm volatile("s_waitcnt lgkmcnt(0)\n" ::: "memory");
    // PV: A = P (transposed LDS read), B = V hi + lo from vbuf
#pragma unroll
    for (int kt = 0; kt < 2; ++kt) {
      int pbyte = lr * 128 + ((kt * 64 + g * 16) ^ ((lr & 7) << 4));
      bf16x8 pa = *(const bf16x8*)(plds + pbyte);
#pragma unroll
      for (int c = 0; c < 4; ++c) {
        int n = c * 16 + lr;
        int swv = (n & 7) << 4;
        bf16x8 vfh = *(const bf16x8*)(vbuf + n * 128 + ((kt * 64 + g * 16) ^ swv));
        bf16x8 vfl =
            *(const bf16x8*)(vbuf + 8192 + n * 128 + ((kt * 64 + g * 16) ^ swv));
        acc[c] = MFMA16(pa, vfh, acc[c]);
        acc[c] = MFMA16(pa, vfl, acc[c]);
      }
    }
    __syncthreads();  // all waves done reading kbuf/vbuf before next stage
  }
  // epilogue: write unnormalized partials
#pragma unroll
  for (int c = 0; c < 4; ++c)
#pragma unroll
    for (int j = 0; j < 4; ++j)
      part_acc[((size_t)split * NROW + qrow0 + g * 4 + j) * DK + c * 16 + lr] =
          acc[c][j];
  if (lr == 0) {
#pragma unroll
    for (int j = 0; j < 4; ++j) {
      part_m[split * NROW + qrow0 + g * 4 + j] = m[j];
      part_l[split * NROW + qrow0 + g * 4 + j] = lsum[j];
    }
  }
}

// ---------------- kernel 2b: combine split-KV partials ----------------
__global__ __launch_bounds__(256) void combine_kernel(
    const float* __restrict__ pacc, const float* __restrict__ pm,
    const float* __restrict__ pl, float* __restrict__ attn_f) {
  int idx = blockIdx.x * 256 + threadIdx.x;
  int row = idx >> 6;
  float m0 = pm[row], m1 = pm[NROW + row];
  float m2 = pm[2 * NROW + row], m3 = pm[3 * NROW + row];
  float M = fmaxf(fmaxf(m0, m1), fmaxf(m2, m3));
  float w0 = __expf(m0 - M), w1 = __expf(m1 - M);
  float w2 = __expf(m2 - M), w3 = __expf(m3 - M);
  float l = w0 * pl[row] + w1 * pl[NROW + row] + w2 * pl[2 * NROW + row] +
            w3 * pl[3 * NROW + row];
  float a = w0 * pacc[idx] + w1 * pacc[(size_t)NROW * DK + idx] +
            w2 * pacc[2 * (size_t)NROW * DK + idx] +
            w3 * pacc[3 * (size_t)NROW * DK + idx];
  attn_f[idx] = a / l;
}

// ---------------- kernel 3: output projection  out = A @ Wo + bo ----------
__global__ __launch_bounds__(256) void oproj_kernel(
    const float* __restrict__ attn, const float* __restrict__ Wo,
    const float* __restrict__ bo, float* __restrict__ out) {
  __shared__ __align__(16) bf16_t wt[256 * 64];  // Wo^T chunk [n][k], swizzled
  const int tid = threadIdx.x;
  const int lane = tid & 63;
  const int wv = tid >> 6;
  const int lr = lane & 15;
  const int g = lane >> 4;
  const int rbase = blockIdx.x * 64 + wv * 16;
  const int c0 = blockIdx.y * 256;
  {  // stage Wo[0..64][c0..c0+256] -> wt[n][k]
    const int k = tid >> 2;
    const int n0 = (tid & 3) << 6;
    const float4* src = (const float4*)(Wo + k * DM + c0 + n0);
#pragma unroll
    for (int i = 0; i < 16; ++i) {
      float4 f = src[i];
      float fv[4] = {f.x, f.y, f.z, f.w};
#pragma unroll
      for (int u = 0; u < 4; ++u) {
        int n = n0 + i * 4 + u;
        int byte = (n << 7) + (k << 1);
        byte ^= (n & 7) << 4;
        *(bf16_t*)((char*)wt + byte) = (bf16_t)fv[u];
      }
    }
  }
  __syncthreads();
  const float* ab = attn + (rbase + lr) * DK + g * 8;
  float4 x0 = *(const float4*)ab;
  float4 x1 = *(const float4*)(ab + 4);
  float4 y0 = *(const float4*)(ab + 32);
  float4 y1 = *(const float4*)(ab + 36);
  float xv[8] = {x0.x, x0.y, x0.z, x0.w, x1.x, x1.y, x1.z, x1.w};
  float yv[8] = {y0.x, y0.y, y0.z, y0.w, y1.x, y1.y, y1.z, y1.w};
  bf16x8 ah0, al0, ah1, al1;
#pragma unroll
  for (int i = 0; i < 8; ++i) {
    ah0[i] = (bf16_t)xv[i];
    al0[i] = (bf16_t)(xv[i] - (float)ah0[i]);
    ah1[i] = (bf16_t)yv[i];
    al1[i] = (bf16_t)(yv[i] - (float)ah1[i]);
  }
  f32x4 acc[16] = {};
#pragma unroll
  for (int c = 0; c < 16; ++c) {
    int n = c * 16 + lr;
    int byte0 = (n << 7) + ((g * 8) << 1);
    byte0 ^= (n & 7) << 4;
    int byte1 = (n << 7) + ((32 + g * 8) << 1);
    byte1 ^= (n & 7) << 4;
    bf16x8 b0 = *(const bf16x8*)((const char*)wt + byte0);
    bf16x8 b1 = *(const bf16x8*)((const char*)wt + byte1);
    acc[c] = MFMA16(ah0, b0, acc[c]);
    acc[c] = MFMA16(al0, b0, acc[c]);
    acc[c] = MFMA16(ah1, b1, acc[c]);
    acc[c] = MFMA16(al1, b1, acc[c]);
  }
#pragma unroll
  for (int c = 0; c < 16; ++c) {
    float bv = bo[c0 + c * 16 + lr];
#pragma unroll
    for (int j = 0; j < 4; ++j)
      out[(rbase + g * 4 + j) * DM + c0 + c * 16 + lr] = acc[c][j] + bv;
  }
}

// ---------------- host launch ----------------
extern "C" void kernel_launch(void* const* d_in, const int* in_sizes, int n_in,
                              void* d_out, int out_size, void* d_ws,
                              size_t ws_size, hipStream_t stream) {
  const float* q = (const float*)d_in[0];
  const float* k = (const float*)d_in[1];
  const float* v = (const float*)d_in[2];
  const int* mask = (const int*)d_in[3];
  const float* Wq = (const float*)d_in[4];
  const float* bq = (const float*)d_in[5];
  const float* Wk = (const float*)d_in[6];
  const float* bk = (const float*)d_in[7];
  const float* Wv = (const float*)d_in[8];
  const float* bv = (const float*)d_in[9];
  const float* Wo = (const float*)d_in[10];
  const float* bo = (const float*)d_in[11];
  float* out = (float*)d_out;

  // workspace layout (~34 MB)
  bf16_t* qhi = (bf16_t*)d_ws;                         // 2MB
  bf16_t* qlo = qhi + (size_t)NROW * DK;               // 2MB
  char* kimg = (char*)(qlo + (size_t)NROW * DK);       // 4MB  [8][32][16KB]
  char* vimg = kimg + ((size_t)NB * 32 << 14);         // 4MB
  char* wimg = vimg + ((size_t)NB * 32 << 14);         // 768KB [3][16][16KB]
  float* part_acc = (float*)(wimg + (size_t)3 * 16 * 16384);  // 16MB
  float* part_m = part_acc + (size_t)NSPLIT * NROW * DK;
  float* part_l = part_m + (size_t)NSPLIT * NROW;
  float* attn_f = part_l + (size_t)NSPLIT * NROW;  // 4MB
  unsigned int* mbits = (unsigned int*)(attn_f + (size_t)NROW * DK);

  maskpack_kernel<<<dim3(SS * (SS / 32) / 256), dim3(256), 0, stream>>>(mask,
                                                                        mbits);
  wprep_kernel<<<dim3(192), dim3(256), 0, stream>>>(Wq, Wk, Wv, wimg);
  proj3_kernel<<<dim3(NROW / 64, 3), dim3(256), 0, stream>>>(
      q, k, v, wimg, bq, bk, bv, qhi, qlo, kimg, vimg);
  attn_kernel<<<dim3(NROW / 64, NSPLIT), dim3(256), 0, stream>>>(
      qhi, qlo, kimg, vimg, mbits, part_acc, part_m, part_l);
  combine_kernel<<<dim3(NROW * DK / 256), dim3(256), 0, stream>>>(
      part_acc, part_m, part_l, attn_f);
  oproj_kernel<<<dim3(NROW / 64, DM / 256), dim3(256), 0, stream>>>(attn_f, Wo,
                                                                    bo, out);
}